// Round 1
// baseline (1493.110 us; speedup 1.0000x reference)
//
#include <hip/hip_runtime.h>
#include <stdint.h>

#define S_ 1024
#define B_ 8
#define D_ 1024
#define H_ 16
#define DK_ 64
#define F_ 4096
#define EPS_ 1e-5f

typedef __bf16 bf16_t;
typedef __attribute__((ext_vector_type(8))) __bf16 bf16x8;
typedef __attribute__((ext_vector_type(4))) __bf16 bf16x4;
typedef __attribute__((ext_vector_type(4))) float f32x4;

// async global->LDS, 16B per lane; LDS dest must be wave-uniform base + lane*16
#define GLD16(gp, lp) __builtin_amdgcn_global_load_lds( \
    (__attribute__((address_space(1))) void*)(void*)(gp), \
    (__attribute__((address_space(3))) void*)(lp), 16, 0, 0)

// ---------------------------------------------------------------------------
// NT GEMM: C[M,N] = A[M,K] * Bt[N,K]^T (+bias), m97-style structure.
// MODE 0: fp32 out, row-major ldc, +bias
// MODE 1: bf16 out scattered to q/k buf [B,H,S,DK]; rows are s*B_+b
// MODE 2: bf16 out scattered to vt buf [B,H,DK,S]
// MODE 3: bf16 out, relu(v+bias), row-major ldc
// MODE 4: fp32 out = v*0.125 into attn region, batched by blockIdx.z
// ---------------------------------------------------------------------------
template<int BM, int BN, int WM, int WN, int MODE>
__global__ __launch_bounds__(256)
void gemm_bt(const bf16_t* __restrict__ A, const bf16_t* __restrict__ Bt,
             const float* __restrict__ bias, void* __restrict__ out,
             int K, int lda, int ldb, int ldc, long batchA, long batchB)
{
    constexpr int MT = WM / 16, NT = WN / 16;
    constexpr int WCOLS = BN / WN;
    __shared__ __align__(16) bf16_t As[BM * 32];
    __shared__ __align__(16) bf16_t Bs[BN * 32];

    const int z = blockIdx.z;
    A += (size_t)z * batchA;
    Bt += (size_t)z * batchB;
    const int rowBase = blockIdx.y * BM;
    const int colBase = blockIdx.x * BN;
    const int tid = threadIdx.x;
    const int wave = tid >> 6, lane = tid & 63;
    const int wr = wave / WCOLS, wc = wave % WCOLS;
    const int lr = lane & 15;
    const int lk = (lane >> 4) * 8;

    f32x4 acc[MT][NT] = {};

    for (int k0 = 0; k0 < K; k0 += 32) {
#pragma unroll
        for (int i = 0; i < BM / 64; ++i) {
            int id = i * 256 + tid;
            GLD16(A + (size_t)(rowBase + (id >> 2)) * lda + k0 + (id & 3) * 8, As + id * 8);
        }
#pragma unroll
        for (int i = 0; i < BN / 64; ++i) {
            int id = i * 256 + tid;
            GLD16(Bt + (size_t)(colBase + (id >> 2)) * ldb + k0 + (id & 3) * 8, Bs + id * 8);
        }
        __syncthreads();
        bf16x8 af[MT], bfr[NT];
#pragma unroll
        for (int mi = 0; mi < MT; ++mi)
            af[mi] = *(const bf16x8*)&As[(wr * WM + mi * 16 + lr) * 32 + lk];
#pragma unroll
        for (int ni = 0; ni < NT; ++ni)
            bfr[ni] = *(const bf16x8*)&Bs[(wc * WN + ni * 16 + lr) * 32 + lk];
#pragma unroll
        for (int mi = 0; mi < MT; ++mi)
#pragma unroll
            for (int ni = 0; ni < NT; ++ni)
                acc[mi][ni] = __builtin_amdgcn_mfma_f32_16x16x32_bf16(af[mi], bfr[ni], acc[mi][ni], 0, 0, 0);
        __syncthreads();
    }

    const int quad = lane >> 4;
#pragma unroll
    for (int mi = 0; mi < MT; ++mi) {
#pragma unroll
        for (int ni = 0; ni < NT; ++ni) {
            const int col = colBase + wc * WN + ni * 16 + lr;
            float bv = 0.f;
            if constexpr (MODE == 0 || MODE == 1 || MODE == 2 || MODE == 3) bv = bias[col];
#pragma unroll
            for (int e = 0; e < 4; ++e) {
                const int row = rowBase + wr * WM + mi * 16 + quad * 4 + e;
                float v = acc[mi][ni][e] + bv;
                if constexpr (MODE == 0) {
                    ((float*)out)[(size_t)row * ldc + col] = v;
                } else if constexpr (MODE == 1) {
                    int s = row >> 3, b = row & 7, h = col >> 6, dk = col & 63;
                    ((bf16_t*)out)[(((size_t)(b * 16 + h) * 1024 + s) << 6) + dk] = (bf16_t)v;
                } else if constexpr (MODE == 2) {
                    int s = row >> 3, b = row & 7, h = col >> 6, dk = col & 63;
                    ((bf16_t*)out)[(((size_t)(b * 16 + h) * 64 + dk) << 10) + s] = (bf16_t)v;
                } else if constexpr (MODE == 3) {
                    ((bf16_t*)out)[(size_t)row * ldc + col] = (bf16_t)fmaxf(v, 0.f);
                } else if constexpr (MODE == 4) {
                    ((float*)out)[((size_t)z << 20) + ((size_t)row << 10) + col] = v * 0.125f;
                }
            }
        }
    }
}

// ---------------------------------------------------------------------------
// PV GEMM: ctx[q,dk] = sum_t attn_f32[q,t] * VT[dk,t]; A staged as fp32 then
// converted to bf16 fragments. One z = (b*H+h). Out ctx rows = s*B_+b.
// ---------------------------------------------------------------------------
__global__ __launch_bounds__(256)
void gemm_pv(const float* __restrict__ attn, const bf16_t* __restrict__ vt,
             bf16_t* __restrict__ ctx)
{
    __shared__ __align__(16) float Asf[128 * 32];
    __shared__ __align__(16) bf16_t Bs[64 * 32];
    const int z = blockIdx.y;
    const int b = z >> 4, h = z & 15;
    const float* Az = attn + ((size_t)z << 20);
    const bf16_t* Bz = vt + ((size_t)z << 16);
    const int rowBase = blockIdx.x * 128;
    const int tid = threadIdx.x;
    const int wave = tid >> 6, lane = tid & 63;
    const int lr = lane & 15, lk = (lane >> 4) * 8;

    f32x4 acc[2][4] = {};

    for (int k0 = 0; k0 < 1024; k0 += 32) {
#pragma unroll
        for (int i = 0; i < 4; ++i) {
            int id = i * 256 + tid;
            GLD16(Az + (((size_t)(rowBase + (id >> 3))) << 10) + k0 + (id & 7) * 4, Asf + id * 4);
        }
        {
            int id = tid;
            GLD16(Bz + (((size_t)(id >> 2)) << 10) + k0 + (id & 3) * 8, Bs + id * 8);
        }
        __syncthreads();
        bf16x8 af[2], bfr[4];
#pragma unroll
        for (int mi = 0; mi < 2; ++mi) {
            const float* p = &Asf[(wave * 32 + mi * 16 + lr) * 32 + lk];
            f32x4 lo = *(const f32x4*)p;
            f32x4 hi = *(const f32x4*)(p + 4);
            bf16x8 a;
#pragma unroll
            for (int j = 0; j < 4; ++j) { a[j] = (bf16_t)lo[j]; a[4 + j] = (bf16_t)hi[j]; }
            af[mi] = a;
        }
#pragma unroll
        for (int ni = 0; ni < 4; ++ni)
            bfr[ni] = *(const bf16x8*)&Bs[(ni * 16 + lr) * 32 + lk];
#pragma unroll
        for (int mi = 0; mi < 2; ++mi)
#pragma unroll
            for (int ni = 0; ni < 4; ++ni)
                acc[mi][ni] = __builtin_amdgcn_mfma_f32_16x16x32_bf16(af[mi], bfr[ni], acc[mi][ni], 0, 0, 0);
        __syncthreads();
    }
    const int quad = lane >> 4;
#pragma unroll
    for (int mi = 0; mi < 2; ++mi)
#pragma unroll
        for (int ni = 0; ni < 4; ++ni) {
            const int col = ni * 16 + lr;
#pragma unroll
            for (int e = 0; e < 4; ++e) {
                const int row = rowBase + wave * 32 + mi * 16 + quad * 4 + e;
                ctx[(((size_t)row * 8 + b) << 10) + h * 64 + col] = (bf16_t)acc[mi][ni][e];
            }
        }
}

// in-place row softmax over attn region; 1 wave per 1024-wide row
__global__ __launch_bounds__(256)
void softmax_inplace(float* __restrict__ attn)
{
    const int wave = threadIdx.x >> 6, lane = threadIdx.x & 63;
    const size_t row = (size_t)blockIdx.x * 4 + wave;
    float4* p = (float4*)(attn + (row << 10));
    float4 v[4];
    float mx = -3.4e38f;
#pragma unroll
    for (int j = 0; j < 4; ++j) {
        v[j] = p[lane + 64 * j];
        mx = fmaxf(mx, fmaxf(fmaxf(v[j].x, v[j].y), fmaxf(v[j].z, v[j].w)));
    }
#pragma unroll
    for (int o = 32; o > 0; o >>= 1) mx = fmaxf(mx, __shfl_xor(mx, o, 64));
    float sum = 0.f;
#pragma unroll
    for (int j = 0; j < 4; ++j) {
        v[j].x = __expf(v[j].x - mx); v[j].y = __expf(v[j].y - mx);
        v[j].z = __expf(v[j].z - mx); v[j].w = __expf(v[j].w - mx);
        sum += v[j].x + v[j].y + v[j].z + v[j].w;
    }
#pragma unroll
    for (int o = 32; o > 0; o >>= 1) sum += __shfl_xor(sum, o, 64);
    const float r = 1.0f / sum;
#pragma unroll
    for (int j = 0; j < 4; ++j) {
        v[j].x *= r; v[j].y *= r; v[j].z *= r; v[j].w *= r;
        p[lane + 64 * j] = v[j];
    }
}

__global__ __launch_bounds__(256)
void prep_kernel(const float* __restrict__ src, const float* __restrict__ pos,
                 bf16_t* __restrict__ qk, bf16_t* __restrict__ vv)
{
    const size_t i = ((size_t)blockIdx.x * 256 + threadIdx.x) * 4;
    float4 s = *(const float4*)(src + i);
    float4 q = *(const float4*)(pos + i);
    bf16x4 qo, vo;
    qo[0] = (bf16_t)(s.x + q.x); qo[1] = (bf16_t)(s.y + q.y);
    qo[2] = (bf16_t)(s.z + q.z); qo[3] = (bf16_t)(s.w + q.w);
    vo[0] = (bf16_t)s.x; vo[1] = (bf16_t)s.y; vo[2] = (bf16_t)s.z; vo[3] = (bf16_t)s.w;
    *(bf16x4*)(qk + i) = qo;
    *(bf16x4*)(vv + i) = vo;
}

// W fp32 [K,N] row-major -> WT bf16 [N,K]
__global__ __launch_bounds__(256)
void transpose_w(const float* __restrict__ W, bf16_t* __restrict__ WT, int K, int N)
{
    __shared__ float t[32][33];
    const int n0 = blockIdx.x * 32, k0 = blockIdx.y * 32;
    const int tx = threadIdx.x & 31;
    const int ty = threadIdx.x >> 5;
#pragma unroll
    for (int j = 0; j < 32; j += 8)
        t[ty + j][tx] = W[(size_t)(k0 + ty + j) * N + n0 + tx];
    __syncthreads();
#pragma unroll
    for (int j = 0; j < 32; j += 8)
        WT[(size_t)(n0 + ty + j) * K + k0 + tx] = (bf16_t)t[tx][ty + j];
}

// LN over D=1024 of (a+b); writes any of xf (fp32), xb (bf16), outf (fp32)
__global__ __launch_bounds__(256)
void ln_kernel(const float* __restrict__ a, const float* __restrict__ b,
               const float* __restrict__ g, const float* __restrict__ be,
               float* __restrict__ xf, bf16_t* __restrict__ xb, float* __restrict__ outf)
{
    __shared__ float sh[8];
    const int r = blockIdx.x;
    const int t = threadIdx.x;
    float4 va = ((const float4*)(a + ((size_t)r << 10)))[t];
    float4 vb = ((const float4*)(b + ((size_t)r << 10)))[t];
    float x0 = va.x + vb.x, x1 = va.y + vb.y, x2 = va.z + vb.z, x3 = va.w + vb.w;
    float s = x0 + x1 + x2 + x3;
    float sq = x0 * x0 + x1 * x1 + x2 * x2 + x3 * x3;
#pragma unroll
    for (int o = 32; o > 0; o >>= 1) { s += __shfl_xor(s, o, 64); sq += __shfl_xor(sq, o, 64); }
    const int w = t >> 6, ln = t & 63;
    if (ln == 0) { sh[w] = s; sh[4 + w] = sq; }
    __syncthreads();
    s = sh[0] + sh[1] + sh[2] + sh[3];
    sq = sh[4] + sh[5] + sh[6] + sh[7];
    const float mean = s * (1.f / 1024.f);
    const float var = sq * (1.f / 1024.f) - mean * mean;
    const float rstd = rsqrtf(var + EPS_);
    float4 vg = ((const float4*)g)[t];
    float4 vbe = ((const float4*)be)[t];
    float y0 = (x0 - mean) * rstd * vg.x + vbe.x;
    float y1 = (x1 - mean) * rstd * vg.y + vbe.y;
    float y2 = (x2 - mean) * rstd * vg.z + vbe.z;
    float y3 = (x3 - mean) * rstd * vg.w + vbe.w;
    if (xf) { float4 o4 = {y0, y1, y2, y3}; ((float4*)(xf + ((size_t)r << 10)))[t] = o4; }
    if (xb) {
        bf16x4 ob; ob[0] = (bf16_t)y0; ob[1] = (bf16_t)y1; ob[2] = (bf16_t)y2; ob[3] = (bf16_t)y3;
        ((bf16x4*)(xb + ((size_t)r << 10)))[t] = ob;
    }
    if (outf) { float4 o4 = {y0, y1, y2, y3}; ((float4*)(outf + ((size_t)r << 10)))[t] = o4; }
}

extern "C" void kernel_launch(void* const* d_in, const int* in_sizes, int n_in,
                              void* d_out, int out_size, void* d_ws, size_t ws_size,
                              hipStream_t stream)
{
    (void)in_sizes; (void)n_in; (void)out_size; (void)ws_size;
    const float* src = (const float*)d_in[0];
    const float* pos = (const float*)d_in[1];
    const float* Wq  = (const float*)d_in[2];
    const float* bq  = (const float*)d_in[3];
    const float* Wk  = (const float*)d_in[4];
    const float* bk  = (const float*)d_in[5];
    const float* Wv  = (const float*)d_in[6];
    const float* bv  = (const float*)d_in[7];
    const float* Wo  = (const float*)d_in[8];
    const float* bo  = (const float*)d_in[9];
    const float* W1  = (const float*)d_in[10];
    const float* b1  = (const float*)d_in[11];
    const float* W2  = (const float*)d_in[12];
    const float* b2  = (const float*)d_in[13];
    const float* g1  = (const float*)d_in[14];
    const float* be1 = (const float*)d_in[15];
    const float* g2  = (const float*)d_in[16];
    const float* be2 = (const float*)d_in[17];

    float* outF  = (float*)d_out;                       // [S,B,D]
    float* attnF = outF + (size_t)S_ * B_ * D_;         // [B,H,S,S]

    char* ws = (char*)d_ws;
    size_t off = 0;
    auto alloc = [&](size_t bytes) { void* p = ws + off; off += (bytes + 255) & ~(size_t)255; return p; };

    bf16_t* qk_bf = (bf16_t*)alloc((size_t)8192 * 1024 * 2);
    bf16_t* v_bf  = (bf16_t*)alloc((size_t)8192 * 1024 * 2);
    bf16_t* wqT   = (bf16_t*)alloc((size_t)1024 * 1024 * 2);
    bf16_t* wkT   = (bf16_t*)alloc((size_t)1024 * 1024 * 2);
    bf16_t* wvT   = (bf16_t*)alloc((size_t)1024 * 1024 * 2);
    bf16_t* woT   = (bf16_t*)alloc((size_t)1024 * 1024 * 2);
    bf16_t* w1T   = (bf16_t*)alloc((size_t)4096 * 1024 * 2);
    bf16_t* w2T   = (bf16_t*)alloc((size_t)1024 * 4096 * 2);
    bf16_t* qbuf  = (bf16_t*)alloc((size_t)8 * 16 * 1024 * 64 * 2);
    bf16_t* kbuf  = (bf16_t*)alloc((size_t)8 * 16 * 1024 * 64 * 2);
    bf16_t* vtbuf = (bf16_t*)alloc((size_t)8 * 16 * 64 * 1024 * 2);
    bf16_t* ctx_bf= (bf16_t*)alloc((size_t)8192 * 1024 * 2);
    float*  ao_f  = (float*)alloc((size_t)8192 * 1024 * 4);
    float*  x_f   = (float*)alloc((size_t)8192 * 1024 * 4);
    bf16_t* x_bf  = (bf16_t*)alloc((size_t)8192 * 1024 * 2);
    bf16_t* h_bf  = (bf16_t*)alloc((size_t)8192 * 4096 * 2);
    float*  y_f   = (float*)alloc((size_t)8192 * 1024 * 4);

    // weights -> bf16 transposed [N,K]
    transpose_w<<<dim3(32, 32), 256, 0, stream>>>(Wq, wqT, 1024, 1024);
    transpose_w<<<dim3(32, 32), 256, 0, stream>>>(Wk, wkT, 1024, 1024);
    transpose_w<<<dim3(32, 32), 256, 0, stream>>>(Wv, wvT, 1024, 1024);
    transpose_w<<<dim3(32, 32), 256, 0, stream>>>(Wo, woT, 1024, 1024);
    transpose_w<<<dim3(128, 32), 256, 0, stream>>>(W1, w1T, 1024, 4096);
    transpose_w<<<dim3(32, 128), 256, 0, stream>>>(W2, w2T, 4096, 1024);

    prep_kernel<<<8192, 256, 0, stream>>>(src, pos, qk_bf, v_bf);

    // projections (rows are s*B+b natural order)
    gemm_bt<128, 128, 64, 64, 1><<<dim3(8, 64, 1), 256, 0, stream>>>(qk_bf, wqT, bq, qbuf, 1024, 1024, 1024, 0, 0, 0);
    gemm_bt<128, 128, 64, 64, 1><<<dim3(8, 64, 1), 256, 0, stream>>>(qk_bf, wkT, bk, kbuf, 1024, 1024, 1024, 0, 0, 0);
    gemm_bt<128, 128, 64, 64, 2><<<dim3(8, 64, 1), 256, 0, stream>>>(v_bf, wvT, bv, vtbuf, 1024, 1024, 1024, 0, 0, 0);

    // scores = Q K^T / 8 into d_out attn region (batched over 128 bh)
    gemm_bt<128, 128, 64, 64, 4><<<dim3(8, 8, 128), 256, 0, stream>>>(qbuf, kbuf, nullptr, attnF, 64, 64, 64, 0, 65536, 65536);
    softmax_inplace<<<32768, 256, 0, stream>>>(attnF);

    // ctx = attn @ V
    gemm_pv<<<dim3(8, 128), 256, 0, stream>>>(attnF, vtbuf, ctx_bf);

    // attn_out = ctx @ Wo + bo
    gemm_bt<128, 128, 64, 64, 0><<<dim3(8, 64, 1), 256, 0, stream>>>(ctx_bf, woT, bo, ao_f, 1024, 1024, 1024, 1024, 0, 0);

    // x = LN(src + attn_out)
    ln_kernel<<<8192, 256, 0, stream>>>(src, ao_f, g1, be1, x_f, x_bf, nullptr);

    // ffn
    gemm_bt<128, 128, 64, 64, 3><<<dim3(32, 64, 1), 256, 0, stream>>>(x_bf, w1T, b1, h_bf, 1024, 1024, 1024, 4096, 0, 0);
    gemm_bt<128, 128, 64, 64, 0><<<dim3(8, 64, 1), 256, 0, stream>>>(h_bf, w2T, b2, y_f, 4096, 4096, 4096, 1024, 0, 0);

    // out = LN(x + ffn)
    ln_kernel<<<8192, 256, 0, stream>>>(x_f, y_f, g2, be2, nullptr, nullptr, outF);
}